// Round 5
// baseline (112.249 us; speedup 1.0000x reference)
//
#include <hip/hip_runtime.h>

#define NBATCH 16384
#define H 16
#define E 64

// Cross-lane-through-LDS phase fence: drain LDS pipe, then stop the
// scheduler from hoisting later ops above it (rule #18).
#define LGKM0 do { asm volatile("s_waitcnt lgkmcnt(0)" ::: "memory"); \
                   __builtin_amdgcn_sched_barrier(0); } while (0)

// One wave per batch. LDS cut to 2 tiles (8.7KB -> 18 blocks/CU, 4.5
// waves/SIMD): mW overlays the dead mean buffer, score lives in registers
// (shuffle softmax), attn^T (16x20) overlays the mW buffer for phase 5.
// All LDS patterns <=2-way bank aliased or broadcast (free on CDNA4).
__global__ __launch_bounds__(64, 5) void ovo_kernel(
    const float* __restrict__ o0, const float* __restrict__ o1,
    const float* __restrict__ o2, const float* __restrict__ o3,
    const float* __restrict__ mn, const float* __restrict__ W,
    float* __restrict__ ctx_out, float* __restrict__ attn_out)
{
    __shared__ float sA[H * 68];     // mean -> mW -> attnT(16x20) overlay
    __shared__ float sMain[H * 68];  // main rows, stride 68

    const int l = threadIdx.x;
    const size_t base = (size_t)blockIdx.x * (H * E);

    // ---- Issue all 20 input loads (coalesced 1KB each); transient regs only.
    float4 ra[4], rb[4], rc[4], rd[4], rv[4];
#pragma unroll
    for (int k = 0; k < 4; ++k) {
        const int off = k * 256 + l * 4;
        ra[k] = *(const float4*)(o0 + base + off);
        rb[k] = *(const float4*)(o1 + base + off);
        rc[k] = *(const float4*)(o2 + base + off);
        rd[k] = *(const float4*)(o3 + base + off);
        rv[k] = *(const float4*)(mn + base + off);
    }

    // ---- Phase 1: mean -> sA, main -> sMain
#pragma unroll
    for (int k = 0; k < 4; ++k) {
        const int flat = k * 256 + l * 4;
        const int h = flat >> 6, e = flat & 63;
        float4 m4;
        m4.x = (ra[k].x + rb[k].x + rc[k].x + rd[k].x) * 0.25f;
        m4.y = (ra[k].y + rb[k].y + rc[k].y + rd[k].y) * 0.25f;
        m4.z = (ra[k].z + rb[k].z + rc[k].z + rd[k].z) * 0.25f;
        m4.w = (ra[k].w + rb[k].w + rc[k].w + rd[k].w) * 0.25f;
        *(float4*)&sA[h * 68 + e] = m4;
        *(float4*)&sMain[h * 68 + e] = rv[k];
    }
    LGKM0;

    // ---- Phase 2: mW[h][f] = sum_e mean[h][e]*W[e][f]  (4x4 tile/lane),
    //      then overlay mW into sA (mean is dead after the reads).
    {
        const int ht = l >> 4, ft = l & 15;
        const int h0 = ht * 4, f0 = ft * 4;
        float acc[4][4] = {{0.f}};
#pragma unroll
        for (int e0 = 0; e0 < 64; e0 += 4) {
            float4 mrow[4], wrow[4];
#pragma unroll
            for (int i = 0; i < 4; ++i) mrow[i] = *(const float4*)&sA[(h0 + i) * 68 + e0];
#pragma unroll
            for (int j = 0; j < 4; ++j) wrow[j] = *(const float4*)&W[(e0 + j) * 64 + f0];
#pragma unroll
            for (int i = 0; i < 4; ++i) {
                const float* mr = (const float*)&mrow[i];
#pragma unroll
                for (int ee = 0; ee < 4; ++ee) {
                    const float* wr = (const float*)&wrow[ee];
#pragma unroll
                    for (int j = 0; j < 4; ++j)
                        acc[i][j] = fmaf(mr[ee], wr[j], acc[i][j]);
                }
            }
        }
        LGKM0;   // all lanes' mean reads retired before the overlay writes
#pragma unroll
        for (int i = 0; i < 4; ++i)
            *(float4*)&sA[(h0 + i) * 68 + f0] =
                make_float4(acc[i][0], acc[i][1], acc[i][2], acc[i][3]);
    }
    LGKM0;

    // ---- Phase 3: score[hp][g0..g0+3] in REGISTERS. lane = hp*4+gp.
    const int hp = l >> 2, gp = l & 3;
    const int g0 = gp * 4;
    float sc[4] = {0.f, 0.f, 0.f, 0.f};
#pragma unroll
    for (int f0 = 0; f0 < 64; f0 += 4) {
        float4 a0 = *(const float4*)&sA[hp * 68 + f0];      // mW row, bcast x4
        const float* pa = (const float*)&a0;
        float4 b[4];
#pragma unroll
        for (int j = 0; j < 4; ++j)
            b[j] = *(const float4*)&sMain[(g0 + j) * 68 + f0];  // bcast x16
#pragma unroll
        for (int j = 0; j < 4; ++j) {
            const float* pb = (const float*)&b[j];
#pragma unroll
            for (int q = 0; q < 4; ++q)
                sc[j] = fmaf(pa[q], pb[q], sc[j]);
        }
    }
    LGKM0;   // insurance: all mW/main reads retired before attnT overlay write

    // ---- Phase 4: shuffle softmax over row hp (4 gp lanes x 4 values)
    {
        float mx = fmaxf(fmaxf(sc[0], sc[1]), fmaxf(sc[2], sc[3]));
        mx = fmaxf(mx, __shfl_xor(mx, 1));
        mx = fmaxf(mx, __shfl_xor(mx, 2));
        float e0 = __expf(sc[0] - mx), e1 = __expf(sc[1] - mx);
        float e2 = __expf(sc[2] - mx), e3 = __expf(sc[3] - mx);
        float sum = (e0 + e1) + (e2 + e3);
        sum += __shfl_xor(sum, 1);
        sum += __shfl_xor(sum, 2);
        const float inv = 1.0f / sum;
        float4 a4 = make_float4(e0 * inv, e1 * inv, e2 * inv, e3 * inv);
        // perfectly coalesced 1KB attn store: lane l covers bytes [16l,16l+16)
        *(float4*)(attn_out + (size_t)blockIdx.x * (H * H) + l * 4) = a4;
        // attn^T into sA overlay (stride 20): banks 2-way max
        const float* pa4 = (const float*)&a4;
#pragma unroll
        for (int j = 0; j < 4; ++j)
            sA[(g0 + j) * 20 + hp] = pa4[j];
    }
    LGKM0;

    // ---- Phase 5: context[h][e] = sum_g attn[h][g]*main[g][e] (4x4 tile)
    {
        const int ht = l >> 4, et = l & 15;
        const int h0 = ht * 4, e0c = et * 4;
        float acc[4][4] = {{0.f}};
#pragma unroll
        for (int g = 0; g < 16; ++g) {
            float4 bv = *(const float4*)&sMain[g * 68 + e0c];
            const float* pb = (const float*)&bv;
            float av[4];
#pragma unroll
            for (int i = 0; i < 4; ++i)
                av[i] = sA[g * 20 + h0 + i];   // 4 addrs, bcast x16: free
#pragma unroll
            for (int i = 0; i < 4; ++i)
#pragma unroll
                for (int j = 0; j < 4; ++j)
                    acc[i][j] = fmaf(av[i], pb[j], acc[i][j]);
        }
        float* cp = ctx_out + base;
#pragma unroll
        for (int i = 0; i < 4; ++i)
            *(float4*)(cp + (h0 + i) * 64 + e0c) =
                make_float4(acc[i][0], acc[i][1], acc[i][2], acc[i][3]);
    }
}

extern "C" void kernel_launch(void* const* d_in, const int* in_sizes, int n_in,
                              void* d_out, int out_size, void* d_ws, size_t ws_size,
                              hipStream_t stream) {
    const float* o0 = (const float*)d_in[0];
    const float* o1 = (const float*)d_in[1];
    const float* o2 = (const float*)d_in[2];
    const float* o3 = (const float*)d_in[3];
    const float* mn = (const float*)d_in[4];
    const float* W  = (const float*)d_in[5];
    float* ctx  = (float*)d_out;
    float* attn = ctx + (size_t)NBATCH * H * E;
    hipLaunchKernelGGL(ovo_kernel, dim3(NBATCH), dim3(64), 0, stream,
                       o0, o1, o2, o3, mn, W, ctx, attn);
}

// Round 6
// 100.797 us; speedup vs baseline: 1.1136x; 1.1136x over previous
//
#include <hip/hip_runtime.h>

#define NBATCH 16384
#define H 16
#define E 64

// Cross-lane-through-LDS phase fence: drain LDS pipe, then stop the
// scheduler from hoisting later ops above it (rule #18).
#define LGKM0 do { asm volatile("s_waitcnt lgkmcnt(0)" ::: "memory"); \
                   __builtin_amdgcn_sched_barrier(0); } while (0)

// One wave per batch. LDS 8.7KB (2 tiles; mW overlays mean, attnT overlays
// mW). Score in registers, quad-shuffle softmax (DPP, VALU-only).
// __launch_bounds__(64,4): VGPR cap 128 — R5's (64,5) cap of ~96 forced a
// scratch spill (VGPR_Count 48, FETCH +39MB, WRITE +78MB). 16 blocks/CU.
// All LDS patterns <=2-way bank aliased or broadcast (free on CDNA4).
__global__ __launch_bounds__(64, 4) void ovo_kernel(
    const float* __restrict__ o0, const float* __restrict__ o1,
    const float* __restrict__ o2, const float* __restrict__ o3,
    const float* __restrict__ mn, const float* __restrict__ W,
    float* __restrict__ ctx_out, float* __restrict__ attn_out)
{
    __shared__ float sA[H * 68];     // mean -> mW -> attnT(16x20) overlay
    __shared__ float sMain[H * 68];  // main rows, stride 68

    const int l = threadIdx.x;
    const size_t base = (size_t)blockIdx.x * (H * E);

    // ---- Issue all 20 input loads (coalesced 1KB each); transient regs only.
    float4 ra[4], rb[4], rc[4], rd[4], rv[4];
#pragma unroll
    for (int k = 0; k < 4; ++k) {
        const int off = k * 256 + l * 4;
        ra[k] = *(const float4*)(o0 + base + off);
        rb[k] = *(const float4*)(o1 + base + off);
        rc[k] = *(const float4*)(o2 + base + off);
        rd[k] = *(const float4*)(o3 + base + off);
        rv[k] = *(const float4*)(mn + base + off);
    }

    // ---- Phase 1: mean -> sA, main -> sMain
#pragma unroll
    for (int k = 0; k < 4; ++k) {
        const int flat = k * 256 + l * 4;
        const int h = flat >> 6, e = flat & 63;
        float4 m4;
        m4.x = (ra[k].x + rb[k].x + rc[k].x + rd[k].x) * 0.25f;
        m4.y = (ra[k].y + rb[k].y + rc[k].y + rd[k].y) * 0.25f;
        m4.z = (ra[k].z + rb[k].z + rc[k].z + rd[k].z) * 0.25f;
        m4.w = (ra[k].w + rb[k].w + rc[k].w + rd[k].w) * 0.25f;
        *(float4*)&sA[h * 68 + e] = m4;
        *(float4*)&sMain[h * 68 + e] = rv[k];
    }
    LGKM0;

    // ---- Phase 2: mW[h][f] = sum_e mean[h][e]*W[e][f]  (4x4 tile/lane),
    //      then overlay mW into sA (mean is dead after the reads).
    {
        const int ht = l >> 4, ft = l & 15;
        const int h0 = ht * 4, f0 = ft * 4;
        float acc[4][4] = {{0.f}};
#pragma unroll
        for (int e0 = 0; e0 < 64; e0 += 4) {
            float4 mrow[4], wrow[4];
#pragma unroll
            for (int i = 0; i < 4; ++i) mrow[i] = *(const float4*)&sA[(h0 + i) * 68 + e0];
#pragma unroll
            for (int j = 0; j < 4; ++j) wrow[j] = *(const float4*)&W[(e0 + j) * 64 + f0];
#pragma unroll
            for (int i = 0; i < 4; ++i) {
                const float* mr = (const float*)&mrow[i];
#pragma unroll
                for (int ee = 0; ee < 4; ++ee) {
                    const float* wr = (const float*)&wrow[ee];
#pragma unroll
                    for (int j = 0; j < 4; ++j)
                        acc[i][j] = fmaf(mr[ee], wr[j], acc[i][j]);
                }
            }
        }
        LGKM0;   // all lanes' mean reads retired before the overlay writes
#pragma unroll
        for (int i = 0; i < 4; ++i)
            *(float4*)&sA[(h0 + i) * 68 + f0] =
                make_float4(acc[i][0], acc[i][1], acc[i][2], acc[i][3]);
    }
    LGKM0;

    // ---- Phase 3: score[hp][g0..g0+3] in REGISTERS. lane = hp*4+gp.
    const int hp = l >> 2, gp = l & 3;
    const int g0 = gp * 4;
    float sc[4] = {0.f, 0.f, 0.f, 0.f};
#pragma unroll
    for (int f0 = 0; f0 < 64; f0 += 4) {
        float4 a0 = *(const float4*)&sA[hp * 68 + f0];      // mW row, bcast x4
        const float* pa = (const float*)&a0;
        float4 b[4];
#pragma unroll
        for (int j = 0; j < 4; ++j)
            b[j] = *(const float4*)&sMain[(g0 + j) * 68 + f0];  // bcast x16
#pragma unroll
        for (int j = 0; j < 4; ++j) {
            const float* pb = (const float*)&b[j];
#pragma unroll
            for (int q = 0; q < 4; ++q)
                sc[j] = fmaf(pa[q], pb[q], sc[j]);
        }
    }
    LGKM0;   // all mW/main reads retired before attnT overlay writes

    // ---- Phase 4: quad softmax over row hp (4 gp lanes x 4 values; DPP)
    {
        float mx = fmaxf(fmaxf(sc[0], sc[1]), fmaxf(sc[2], sc[3]));
        mx = fmaxf(mx, __shfl_xor(mx, 1));
        mx = fmaxf(mx, __shfl_xor(mx, 2));
        float e0 = __expf(sc[0] - mx), e1 = __expf(sc[1] - mx);
        float e2 = __expf(sc[2] - mx), e3 = __expf(sc[3] - mx);
        float sum = (e0 + e1) + (e2 + e3);
        sum += __shfl_xor(sum, 1);
        sum += __shfl_xor(sum, 2);
        const float inv = 1.0f / sum;
        float4 a4 = make_float4(e0 * inv, e1 * inv, e2 * inv, e3 * inv);
        // perfectly coalesced 1KB attn store: lane l covers bytes [16l,16l+16)
        *(float4*)(attn_out + (size_t)blockIdx.x * (H * H) + l * 4) = a4;
        // attn^T into sA overlay (stride 20): 2-way banks max
        const float* pa4 = (const float*)&a4;
#pragma unroll
        for (int j = 0; j < 4; ++j)
            sA[(g0 + j) * 20 + hp] = pa4[j];
    }
    LGKM0;

    // ---- Phase 5: context[h][e] = sum_g attn[h][g]*main[g][e] (4x4 tile).
    //      attnT rows read as float4 (16B-aligned: (20g+4ht)*4 % 16 == 0;
    //      4 distinct chunks x16-lane broadcast = conflict-free).
    {
        const int ht = l >> 4, et = l & 15;
        const int h0 = ht * 4, e0c = et * 4;
        float acc[4][4] = {{0.f}};
#pragma unroll
        for (int g = 0; g < 16; ++g) {
            float4 bv = *(const float4*)&sMain[g * 68 + e0c];
            float4 av = *(const float4*)&sA[g * 20 + h0];   // attnT[g][h0..h0+3]
            const float* pb = (const float*)&bv;
            const float* pa = (const float*)&av;
#pragma unroll
            for (int i = 0; i < 4; ++i)
#pragma unroll
                for (int j = 0; j < 4; ++j)
                    acc[i][j] = fmaf(pa[i], pb[j], acc[i][j]);
        }
        float* cp = ctx_out + base;
#pragma unroll
        for (int i = 0; i < 4; ++i)
            *(float4*)(cp + (h0 + i) * 64 + e0c) =
                make_float4(acc[i][0], acc[i][1], acc[i][2], acc[i][3]);
    }
}

extern "C" void kernel_launch(void* const* d_in, const int* in_sizes, int n_in,
                              void* d_out, int out_size, void* d_ws, size_t ws_size,
                              hipStream_t stream) {
    const float* o0 = (const float*)d_in[0];
    const float* o1 = (const float*)d_in[1];
    const float* o2 = (const float*)d_in[2];
    const float* o3 = (const float*)d_in[3];
    const float* mn = (const float*)d_in[4];
    const float* W  = (const float*)d_in[5];
    float* ctx  = (float*)d_out;
    float* attn = ctx + (size_t)NBATCH * H * E;
    hipLaunchKernelGGL(ovo_kernel, dim3(NBATCH), dim3(64), 0, stream,
                       o0, o1, o2, o3, mn, W, ctx, attn);
}

// Round 7
// 91.692 us; speedup vs baseline: 1.2242x; 1.0993x over previous
//
#include <hip/hip_runtime.h>

#define NBATCH 16384
#define H 16
#define E 64

// Cross-lane-through-LDS phase fence: drain LDS pipe, then stop the
// scheduler from hoisting later ops above it (rule #18).
#define LGKM0 do { asm volatile("s_waitcnt lgkmcnt(0)" ::: "memory"); \
                   __builtin_amdgcn_sched_barrier(0); } while (0)

// One wave per batch. LDS 8.7KB (2 tiles; mW overlays mean, attnT overlays
// mW). Score in registers, quad-shuffle softmax (VALU-only).
// __launch_bounds__(64,3): cap 170. Empirical allocator behavior on this
// body: (64,5)->48 VGPR + spill, (64,4)->64 VGPR + spill (allocator rounds
// down to the next occupancy step and spills); (64,3) is the only observed
// spill-free config (R4: 84 VGPR, FETCH/WRITE at ideal 164/82MB).
// All LDS patterns <=2-way bank aliased or broadcast (free on CDNA4).
__global__ __launch_bounds__(64, 3) void ovo_kernel(
    const float* __restrict__ o0, const float* __restrict__ o1,
    const float* __restrict__ o2, const float* __restrict__ o3,
    const float* __restrict__ mn, const float* __restrict__ W,
    float* __restrict__ ctx_out, float* __restrict__ attn_out)
{
    __shared__ float sA[H * 68];     // mean -> mW -> attnT(16x20) overlay
    __shared__ float sMain[H * 68];  // main rows, stride 68

    const int l = threadIdx.x;
    const size_t base = (size_t)blockIdx.x * (H * E);

    // ---- Issue all 20 input loads (coalesced 1KB each); transient regs only.
    float4 ra[4], rb[4], rc[4], rd[4], rv[4];
#pragma unroll
    for (int k = 0; k < 4; ++k) {
        const int off = k * 256 + l * 4;
        ra[k] = *(const float4*)(o0 + base + off);
        rb[k] = *(const float4*)(o1 + base + off);
        rc[k] = *(const float4*)(o2 + base + off);
        rd[k] = *(const float4*)(o3 + base + off);
        rv[k] = *(const float4*)(mn + base + off);
    }

    // ---- Phase 1: mean -> sA, main -> sMain
#pragma unroll
    for (int k = 0; k < 4; ++k) {
        const int flat = k * 256 + l * 4;
        const int h = flat >> 6, e = flat & 63;
        float4 m4;
        m4.x = (ra[k].x + rb[k].x + rc[k].x + rd[k].x) * 0.25f;
        m4.y = (ra[k].y + rb[k].y + rc[k].y + rd[k].y) * 0.25f;
        m4.z = (ra[k].z + rb[k].z + rc[k].z + rd[k].z) * 0.25f;
        m4.w = (ra[k].w + rb[k].w + rc[k].w + rd[k].w) * 0.25f;
        *(float4*)&sA[h * 68 + e] = m4;
        *(float4*)&sMain[h * 68 + e] = rv[k];
    }
    LGKM0;

    // ---- Phase 2: mW[h][f] = sum_e mean[h][e]*W[e][f]  (4x4 tile/lane),
    //      then overlay mW into sA (mean is dead after the reads).
    {
        const int ht = l >> 4, ft = l & 15;
        const int h0 = ht * 4, f0 = ft * 4;
        float acc[4][4] = {{0.f}};
#pragma unroll
        for (int e0 = 0; e0 < 64; e0 += 4) {
            float4 mrow[4], wrow[4];
#pragma unroll
            for (int i = 0; i < 4; ++i) mrow[i] = *(const float4*)&sA[(h0 + i) * 68 + e0];
#pragma unroll
            for (int j = 0; j < 4; ++j) wrow[j] = *(const float4*)&W[(e0 + j) * 64 + f0];
#pragma unroll
            for (int i = 0; i < 4; ++i) {
                const float* mr = (const float*)&mrow[i];
#pragma unroll
                for (int ee = 0; ee < 4; ++ee) {
                    const float* wr = (const float*)&wrow[ee];
#pragma unroll
                    for (int j = 0; j < 4; ++j)
                        acc[i][j] = fmaf(mr[ee], wr[j], acc[i][j]);
                }
            }
        }
        LGKM0;   // all lanes' mean reads retired before the overlay writes
#pragma unroll
        for (int i = 0; i < 4; ++i)
            *(float4*)&sA[(h0 + i) * 68 + f0] =
                make_float4(acc[i][0], acc[i][1], acc[i][2], acc[i][3]);
    }
    LGKM0;

    // ---- Phase 3: score[hp][g0..g0+3] in REGISTERS. lane = hp*4+gp.
    const int hp = l >> 2, gp = l & 3;
    const int g0 = gp * 4;
    float sc[4] = {0.f, 0.f, 0.f, 0.f};
#pragma unroll
    for (int f0 = 0; f0 < 64; f0 += 4) {
        float4 a0 = *(const float4*)&sA[hp * 68 + f0];      // mW row, bcast x4
        const float* pa = (const float*)&a0;
        float4 b[4];
#pragma unroll
        for (int j = 0; j < 4; ++j)
            b[j] = *(const float4*)&sMain[(g0 + j) * 68 + f0];  // bcast x16
#pragma unroll
        for (int j = 0; j < 4; ++j) {
            const float* pb = (const float*)&b[j];
#pragma unroll
            for (int q = 0; q < 4; ++q)
                sc[j] = fmaf(pa[q], pb[q], sc[j]);
        }
    }
    LGKM0;   // all mW/main reads retired before attnT overlay writes

    // ---- Phase 4: quad softmax over row hp (4 gp lanes x 4 values)
    {
        float mx = fmaxf(fmaxf(sc[0], sc[1]), fmaxf(sc[2], sc[3]));
        mx = fmaxf(mx, __shfl_xor(mx, 1));
        mx = fmaxf(mx, __shfl_xor(mx, 2));
        float e0 = __expf(sc[0] - mx), e1 = __expf(sc[1] - mx);
        float e2 = __expf(sc[2] - mx), e3 = __expf(sc[3] - mx);
        float sum = (e0 + e1) + (e2 + e3);
        sum += __shfl_xor(sum, 1);
        sum += __shfl_xor(sum, 2);
        const float inv = 1.0f / sum;
        float4 a4 = make_float4(e0 * inv, e1 * inv, e2 * inv, e3 * inv);
        // perfectly coalesced 1KB attn store: lane l covers bytes [16l,16l+16)
        *(float4*)(attn_out + (size_t)blockIdx.x * (H * H) + l * 4) = a4;
        // attn^T into sA overlay (stride 20): 2-way banks max
        const float* pa4 = (const float*)&a4;
#pragma unroll
        for (int j = 0; j < 4; ++j)
            sA[(g0 + j) * 20 + hp] = pa4[j];
    }
    LGKM0;

    // ---- Phase 5: context[h][e] = sum_g attn[h][g]*main[g][e] (4x4 tile).
    //      attnT rows read as float4 (16B-aligned: (20g+4ht)*4 % 16 == 0;
    //      4 distinct chunks x16-lane broadcast = conflict-free).
    {
        const int ht = l >> 4, et = l & 15;
        const int h0 = ht * 4, e0c = et * 4;
        float acc[4][4] = {{0.f}};
#pragma unroll
        for (int g = 0; g < 16; ++g) {
            float4 bv = *(const float4*)&sMain[g * 68 + e0c];
            float4 av = *(const float4*)&sA[g * 20 + h0];   // attnT[g][h0..h0+3]
            const float* pb = (const float*)&bv;
            const float* pa = (const float*)&av;
#pragma unroll
            for (int i = 0; i < 4; ++i)
#pragma unroll
                for (int j = 0; j < 4; ++j)
                    acc[i][j] = fmaf(pa[i], pb[j], acc[i][j]);
        }
        float* cp = ctx_out + base;
#pragma unroll
        for (int i = 0; i < 4; ++i)
            *(float4*)(cp + (h0 + i) * 64 + e0c) =
                make_float4(acc[i][0], acc[i][1], acc[i][2], acc[i][3]);
    }
}

extern "C" void kernel_launch(void* const* d_in, const int* in_sizes, int n_in,
                              void* d_out, int out_size, void* d_ws, size_t ws_size,
                              hipStream_t stream) {
    const float* o0 = (const float*)d_in[0];
    const float* o1 = (const float*)d_in[1];
    const float* o2 = (const float*)d_in[2];
    const float* o3 = (const float*)d_in[3];
    const float* mn = (const float*)d_in[4];
    const float* W  = (const float*)d_in[5];
    float* ctx  = (float*)d_out;
    float* attn = ctx + (size_t)NBATCH * H * E;
    hipLaunchKernelGGL(ovo_kernel, dim3(NBATCH), dim3(64), 0, stream,
                       o0, o1, o2, o3, mn, W, ctx, attn);
}